// Round 5
// baseline (441.383 us; speedup 1.0000x reference)
//
#include <hip/hip_runtime.h>
#include <hip/hip_bf16.h>

#define N_NODES 50000
#define N_EDGES 800000
#define IN_DIM 128
#define OUT_DIM 64
#define REL_DIM 32
#define NEG_SLOPE 0.01f
#define NB 391            // coarse buckets: 128 dst nodes each (391*128 = 50048)
#define K3_TILE 2048
#define K3_BLOCKS ((N_EDGES + K3_TILE - 1) / K3_TILE)   // 391

// ================= K1: z = h @ Wfc^T (register-tiled, b128 LDS reads), s1/s2 fused ============
__global__ __launch_bounds__(256) void k1_fc(const float* __restrict__ h,
                                             const float* __restrict__ Wfc,
                                             const float* __restrict__ Wattn,
                                             __hip_bfloat16* __restrict__ zb,
                                             float* __restrict__ s1,
                                             float* __restrict__ s2) {
    __shared__ float Wl[64][68];   // [k_local][c]
    __shared__ float hl[64][68];   // [k_local][n]
    const int t = threadIdx.x;
    const int cg = t & 15, ng = t >> 4;
    const int c0 = cg * 4;
    float wa1[4], wa2[4];
#pragma unroll
    for (int j = 0; j < 4; ++j) { wa1[j] = Wattn[c0 + j]; wa2[j] = Wattn[96 + c0 + j]; }

    const int n0 = blockIdx.x * 64;
    float acc[4][4] = {};
    const float4* W4 = (const float4*)Wfc;   // [64][32] float4
    const float4* h4 = (const float4*)h;     // [N][32] float4

#pragma unroll
    for (int H = 0; H < 2; ++H) {
        __syncthreads();
#pragma unroll
        for (int i = 0; i < 4; ++i) {
            int idx = t + 256 * i;
            int c = idx & 63, k4 = idx >> 6;
            float4 v = W4[c * 32 + H * 16 + k4];
            Wl[4*k4+0][c] = v.x; Wl[4*k4+1][c] = v.y;
            Wl[4*k4+2][c] = v.z; Wl[4*k4+3][c] = v.w;
        }
#pragma unroll
        for (int i = 0; i < 4; ++i) {
            int idx = t + 256 * i;
            int n = idx & 63, k4 = idx >> 6;
            int gn = n0 + n; if (gn > N_NODES - 1) gn = N_NODES - 1;
            float4 v = h4[(size_t)gn * 32 + H * 16 + k4];
            hl[4*k4+0][n] = v.x; hl[4*k4+1][n] = v.y;
            hl[4*k4+2][n] = v.z; hl[4*k4+3][n] = v.w;
        }
        __syncthreads();
#pragma unroll 8
        for (int k = 0; k < 64; ++k) {
            float4 wv = *(const float4*)&Wl[k][c0];
            float4 hv = *(const float4*)&hl[k][ng * 4];
            float wvf[4] = {wv.x, wv.y, wv.z, wv.w};
            float hvf[4] = {hv.x, hv.y, hv.z, hv.w};
#pragma unroll
            for (int i = 0; i < 4; ++i)
#pragma unroll
                for (int j = 0; j < 4; ++j) acc[i][j] += hvf[i] * wvf[j];
        }
    }

#pragma unroll
    for (int i = 0; i < 4; ++i) {
        int gn = n0 + ng * 4 + i;
        float r1 = acc[i][0]*wa1[0] + acc[i][1]*wa1[1] + acc[i][2]*wa1[2] + acc[i][3]*wa1[3];
        float r2 = acc[i][0]*wa2[0] + acc[i][1]*wa2[1] + acc[i][2]*wa2[2] + acc[i][3]*wa2[3];
#pragma unroll
        for (int off = 1; off < 16; off <<= 1) {
            r1 += __shfl_xor(r1, off, 64);
            r2 += __shfl_xor(r2, off, 64);
        }
        if (gn < N_NODES) {
            __hip_bfloat16 b0 = __float2bfloat16(acc[i][0]);
            __hip_bfloat16 b1 = __float2bfloat16(acc[i][1]);
            __hip_bfloat16 b2 = __float2bfloat16(acc[i][2]);
            __hip_bfloat16 b3 = __float2bfloat16(acc[i][3]);
            ushort4 st;
            st.x = *(unsigned short*)&b0; st.y = *(unsigned short*)&b1;
            st.z = *(unsigned short*)&b2; st.w = *(unsigned short*)&b3;
            ((ushort4*)zb)[(size_t)gn * 16 + cg] = st;
            if (cg == 0) { s1[gn] = r1; s2[gn] = r2; }
        }
    }
}

// ================= K2: coarse-bucket histogram of dst =================
__global__ __launch_bounds__(256) void k2_count(const int* __restrict__ dst,
                                                unsigned* __restrict__ gcount) {
    __shared__ unsigned hist[NB];
    const int t = threadIdx.x;
    for (int b = t; b < NB; b += 256) hist[b] = 0;
    __syncthreads();
    const int stride = gridDim.x * blockDim.x;
    for (int e = blockIdx.x * blockDim.x + t; e < N_EDGES; e += stride)
        atomicAdd(&hist[dst[e] >> 7], 1u);
    __syncthreads();
    for (int b = t; b < NB; b += 256)
        if (hist[b]) atomicAdd(&gcount[b], hist[b]);
}

// ================= scan over NB buckets -> offs_b, padded cursors =================
__global__ __launch_bounds__(512) void scan_buckets(const unsigned* __restrict__ gcount,
                                                    unsigned* __restrict__ offs_b,
                                                    unsigned* __restrict__ ccur) {
    __shared__ unsigned sd[512];
    const int t = threadIdx.x;
    unsigned v = (t < NB) ? gcount[t] : 0u;
    sd[t] = v;
    __syncthreads();
#pragma unroll
    for (int off = 1; off < 512; off <<= 1) {
        unsigned tmp = (t >= off) ? sd[t - off] : 0u;
        __syncthreads();
        sd[t] += tmp;
        __syncthreads();
    }
    if (t < NB) {
        unsigned ex = sd[t] - v;
        offs_b[t] = ex;
        ccur[t * 16] = ex;   // 64B-strided cursors (one line each)
    }
    if (t == 0) offs_b[NB] = N_EDGES;
}

// ================= K3: logits + leaky-relu + LDS-staged coarse binning ========================
// pair item: (ev, aux) with aux = src | (d_local << 16); src < 65536, d_local < 128.
__global__ __launch_bounds__(256) void k3_fused(const float* __restrict__ p,
                                                const int* __restrict__ src,
                                                const int* __restrict__ dst,
                                                const float* __restrict__ Wattn,
                                                const float* __restrict__ s1,
                                                const float* __restrict__ s2,
                                                unsigned* __restrict__ ccur,
                                                float2* __restrict__ pair) {
    __shared__ float wp[REL_DIM];
    __shared__ unsigned hist[NB];
    __shared__ unsigned gb[NB];
    __shared__ unsigned lcur[NB];
    const int t = threadIdx.x;
    if (t < REL_DIM) wp[t] = Wattn[64 + t];
    for (int b = t; b < NB; b += 256) hist[b] = 0;
    __syncthreads();

    const int base = blockIdx.x * K3_TILE;
    float evr[8];
    unsigned auxr[8];
    short br[8];
#pragma unroll
    for (int i = 0; i < 8; ++i) {
        int e = base + i * 256 + t;
        if (e < N_EDGES) {
            int s = src[e], d = dst[e];
            const float4* pe = (const float4*)(p + (size_t)e * REL_DIM);
            float dotp = 0.f;
#pragma unroll
            for (int q = 0; q < 8; ++q) {
                float4 v = pe[q];
                dotp += v.x*wp[q*4+0] + v.y*wp[q*4+1] + v.z*wp[q*4+2] + v.w*wp[q*4+3];
            }
            float a = s1[s] + dotp + s2[d];
            evr[i] = a > 0.f ? a : NEG_SLOPE * a;
            auxr[i] = (unsigned)s | ((unsigned)(d & 127) << 16);
            int b = d >> 7;
            br[i] = (short)b;
            atomicAdd(&hist[b], 1u);
        } else br[i] = -1;
    }
    __syncthreads();
    // one global reservation per (block,bucket)
    for (int b = t; b < NB; b += 256) {
        lcur[b] = 0;
        gb[b] = hist[b] ? atomicAdd(&ccur[b * 16], hist[b]) : 0u;
    }
    __syncthreads();
#pragma unroll
    for (int i = 0; i < 8; ++i) {
        if (br[i] >= 0) {
            int b = br[i];
            unsigned pos = atomicAdd(&lcur[b], 1u);
            pair[gb[b] + pos] = make_float2(evr[i], __uint_as_float(auxr[i]));
        }
    }
}

// ================= K4: block-per-bucket LDS accumulation + normalize =================
__global__ __launch_bounds__(512) void k4_agg(const unsigned* __restrict__ offs_b,
                                              const float2* __restrict__ pair,
                                              const __hip_bfloat16* __restrict__ zb,
                                              float* __restrict__ out) {
    __shared__ float acc[128 * 64];   // 32KB
    __shared__ float den[128];
    const int t = threadIdx.x;
    const int lane = t & 63, wid = t >> 6;   // 8 waves
    for (int i = t; i < 128 * 64; i += 512) acc[i] = 0.f;
    if (t < 128) den[t] = 0.f;
    __syncthreads();
    const int b = blockIdx.x;
    const int lo = offs_b[b], hi = offs_b[b + 1];
    for (int i = lo + wid; i < hi; i += 8) {
        float2 it = pair[i];                       // wave-uniform 8B load
        unsigned aux = __float_as_uint(it.y);
        float num = __expf(it.x);
        int s = aux & 0xFFFF;
        int dl = aux >> 16;
        float zv = __bfloat162float(zb[(size_t)s * OUT_DIM + lane]);
        atomicAdd(&acc[dl * 64 + lane], num * zv);
        if (lane == 0) atomicAdd(&den[dl], num);
    }
    __syncthreads();
    const int n0 = b * 128;
    for (int i = t; i < 128 * 64; i += 512) {
        int dl = i >> 6, gn = n0 + dl;
        if (gn < N_NODES) {
            float d = den[dl];
            out[(size_t)gn * 64 + (i & 63)] = (d != 0.f) ? acc[i] / d : 0.f;
        }
    }
}

extern "C" void kernel_launch(void* const* d_in, const int* in_sizes, int n_in,
                              void* d_out, int out_size, void* d_ws, size_t ws_size,
                              hipStream_t stream) {
    const float* h     = (const float*)d_in[0];
    const float* p     = (const float*)d_in[1];
    const int*   src   = (const int*)d_in[2];
    const int*   dst   = (const int*)d_in[3];
    const float* Wfc   = (const float*)d_in[4];
    const float* Wattn = (const float*)d_in[5];
    float* out = (float*)d_out;

    // workspace layout (float words)
    float* ws = (float*)d_ws;
    __hip_bfloat16* zb = (__hip_bfloat16*)ws;        // 3,200,000 bf16 = 1,600,000 floats
    float*    s1     = ws + 1600000;                 // 50,000
    float*    s2     = ws + 1650000;                 // 50,000
    unsigned* gcount = (unsigned*)(ws + 1700000);    // 512
    unsigned* offs_b = (unsigned*)(ws + 1700512);    // 512 (NB+1 used)
    unsigned* ccur   = (unsigned*)(ws + 1701024);    // 391*16 = 6256 -> 6272
    float2*   pair   = (float2*)(ws + 1707296);      // 800,000 float2 (16B-aligned)
    // total: 3,307,296 floats = 13.2 MB

    hipMemsetAsync(gcount, 0, 512 * sizeof(unsigned), stream);

    k1_fc<<<(N_NODES + 63) / 64, 256, 0, stream>>>(h, Wfc, Wattn, zb, s1, s2);
    k2_count<<<K3_BLOCKS, 256, 0, stream>>>(dst, gcount);
    scan_buckets<<<1, 512, 0, stream>>>(gcount, offs_b, ccur);
    k3_fused<<<K3_BLOCKS, 256, 0, stream>>>(p, src, dst, Wattn, s1, s2, ccur, pair);
    k4_agg<<<NB, 512, 0, stream>>>(offs_b, pair, zb, out);
}

// Round 6
// 123.680 us; speedup vs baseline: 3.5688x; 3.5688x over previous
//
#include <hip/hip_runtime.h>
#include <hip/hip_bf16.h>

#define N_NODES 50000
#define N_EDGES 800000
#define IN_DIM 128
#define OUT_DIM 64
#define REL_DIM 32
#define NEG_SLOPE 0.01f
#define NB 391            // coarse buckets: 128 dst nodes each (391*128 = 50048)
#define K3_TILE 2048
#define K3_BLOCKS ((N_EDGES + K3_TILE - 1) / K3_TILE)   // 391
#define BCAP 3072         // bucket capacity for k3b LDS staging (mean 2046, sigma 45)

// ================= K1: z = h @ Wfc^T (register-tiled, b128 LDS reads), s1/s2 fused ============
__global__ __launch_bounds__(256) void k1_fc(const float* __restrict__ h,
                                             const float* __restrict__ Wfc,
                                             const float* __restrict__ Wattn,
                                             __hip_bfloat16* __restrict__ zb,
                                             float* __restrict__ s1,
                                             float* __restrict__ s2) {
    __shared__ float Wl[64][68];   // [k_local][c]
    __shared__ float hl[64][68];   // [k_local][n]
    const int t = threadIdx.x;
    const int cg = t & 15, ng = t >> 4;
    const int c0 = cg * 4;
    float wa1[4], wa2[4];
#pragma unroll
    for (int j = 0; j < 4; ++j) { wa1[j] = Wattn[c0 + j]; wa2[j] = Wattn[96 + c0 + j]; }

    const int n0 = blockIdx.x * 64;
    float acc[4][4] = {};
    const float4* W4 = (const float4*)Wfc;   // [64][32] float4
    const float4* h4 = (const float4*)h;     // [N][32] float4

#pragma unroll
    for (int H = 0; H < 2; ++H) {
        __syncthreads();
#pragma unroll
        for (int i = 0; i < 4; ++i) {
            int idx = t + 256 * i;
            int c = idx & 63, k4 = idx >> 6;
            float4 v = W4[c * 32 + H * 16 + k4];
            Wl[4*k4+0][c] = v.x; Wl[4*k4+1][c] = v.y;
            Wl[4*k4+2][c] = v.z; Wl[4*k4+3][c] = v.w;
        }
#pragma unroll
        for (int i = 0; i < 4; ++i) {
            int idx = t + 256 * i;
            int n = idx & 63, k4 = idx >> 6;
            int gn = n0 + n; if (gn > N_NODES - 1) gn = N_NODES - 1;
            float4 v = h4[(size_t)gn * 32 + H * 16 + k4];
            hl[4*k4+0][n] = v.x; hl[4*k4+1][n] = v.y;
            hl[4*k4+2][n] = v.z; hl[4*k4+3][n] = v.w;
        }
        __syncthreads();
#pragma unroll 8
        for (int k = 0; k < 64; ++k) {
            float4 wv = *(const float4*)&Wl[k][c0];
            float4 hv = *(const float4*)&hl[k][ng * 4];
            float wvf[4] = {wv.x, wv.y, wv.z, wv.w};
            float hvf[4] = {hv.x, hv.y, hv.z, hv.w};
#pragma unroll
            for (int i = 0; i < 4; ++i)
#pragma unroll
                for (int j = 0; j < 4; ++j) acc[i][j] += hvf[i] * wvf[j];
        }
    }

#pragma unroll
    for (int i = 0; i < 4; ++i) {
        int gn = n0 + ng * 4 + i;
        float r1 = acc[i][0]*wa1[0] + acc[i][1]*wa1[1] + acc[i][2]*wa1[2] + acc[i][3]*wa1[3];
        float r2 = acc[i][0]*wa2[0] + acc[i][1]*wa2[1] + acc[i][2]*wa2[2] + acc[i][3]*wa2[3];
#pragma unroll
        for (int off = 1; off < 16; off <<= 1) {
            r1 += __shfl_xor(r1, off, 64);
            r2 += __shfl_xor(r2, off, 64);
        }
        if (gn < N_NODES) {
            __hip_bfloat16 b0 = __float2bfloat16(acc[i][0]);
            __hip_bfloat16 b1 = __float2bfloat16(acc[i][1]);
            __hip_bfloat16 b2 = __float2bfloat16(acc[i][2]);
            __hip_bfloat16 b3 = __float2bfloat16(acc[i][3]);
            ushort4 st;
            st.x = *(unsigned short*)&b0; st.y = *(unsigned short*)&b1;
            st.z = *(unsigned short*)&b2; st.w = *(unsigned short*)&b3;
            ((ushort4*)zb)[(size_t)gn * 16 + cg] = st;
            if (cg == 0) { s1[gn] = r1; s2[gn] = r2; }
        }
    }
}

// ================= K2: coarse-bucket histogram of dst =================
__global__ __launch_bounds__(256) void k2_count(const int* __restrict__ dst,
                                                unsigned* __restrict__ gcount) {
    __shared__ unsigned hist[NB];
    const int t = threadIdx.x;
    for (int b = t; b < NB; b += 256) hist[b] = 0;
    __syncthreads();
    const int stride = gridDim.x * blockDim.x;
    for (int e = blockIdx.x * blockDim.x + t; e < N_EDGES; e += stride)
        atomicAdd(&hist[dst[e] >> 7], 1u);
    __syncthreads();
    for (int b = t; b < NB; b += 256)
        if (hist[b]) atomicAdd(&gcount[b], hist[b]);
}

// ================= scan over NB buckets -> offs_b, padded cursors =================
__global__ __launch_bounds__(512) void scan_buckets(const unsigned* __restrict__ gcount,
                                                    unsigned* __restrict__ offs_b,
                                                    unsigned* __restrict__ ccur) {
    __shared__ unsigned sd[512];
    const int t = threadIdx.x;
    unsigned v = (t < NB) ? gcount[t] : 0u;
    sd[t] = v;
    __syncthreads();
#pragma unroll
    for (int off = 1; off < 512; off <<= 1) {
        unsigned tmp = (t >= off) ? sd[t - off] : 0u;
        __syncthreads();
        sd[t] += tmp;
        __syncthreads();
    }
    if (t < NB) {
        unsigned ex = sd[t] - v;
        offs_b[t] = ex;
        ccur[t * 16] = ex;   // 64B-strided cursors
    }
    if (t == 0) offs_b[NB] = N_EDGES;
}

// ================= K3: logits + leaky-relu + LDS-staged coarse binning ========================
// pair item: (ev, aux) with aux = src | (d_local << 16)
__global__ __launch_bounds__(256) void k3_fused(const float* __restrict__ p,
                                                const int* __restrict__ src,
                                                const int* __restrict__ dst,
                                                const float* __restrict__ Wattn,
                                                const float* __restrict__ s1,
                                                const float* __restrict__ s2,
                                                unsigned* __restrict__ ccur,
                                                float2* __restrict__ pair) {
    __shared__ float wp[REL_DIM];
    __shared__ unsigned hist[NB];
    __shared__ unsigned gb[NB];
    __shared__ unsigned lcur[NB];
    const int t = threadIdx.x;
    if (t < REL_DIM) wp[t] = Wattn[64 + t];
    for (int b = t; b < NB; b += 256) hist[b] = 0;
    __syncthreads();

    const int base = blockIdx.x * K3_TILE;
    float evr[8];
    unsigned auxr[8];
    short br[8];
#pragma unroll
    for (int i = 0; i < 8; ++i) {
        int e = base + i * 256 + t;
        if (e < N_EDGES) {
            int s = src[e], d = dst[e];
            const float4* pe = (const float4*)(p + (size_t)e * REL_DIM);
            float dotp = 0.f;
#pragma unroll
            for (int q = 0; q < 8; ++q) {
                float4 v = pe[q];
                dotp += v.x*wp[q*4+0] + v.y*wp[q*4+1] + v.z*wp[q*4+2] + v.w*wp[q*4+3];
            }
            float a = s1[s] + dotp + s2[d];
            evr[i] = a > 0.f ? a : NEG_SLOPE * a;
            auxr[i] = (unsigned)s | ((unsigned)(d & 127) << 16);
            int b = d >> 7;
            br[i] = (short)b;
            atomicAdd(&hist[b], 1u);
        } else br[i] = -1;
    }
    __syncthreads();
    for (int b = t; b < NB; b += 256) {
        lcur[b] = 0;
        gb[b] = hist[b] ? atomicAdd(&ccur[b * 16], hist[b]) : 0u;
    }
    __syncthreads();
#pragma unroll
    for (int i = 0; i < 8; ++i) {
        if (br[i] >= 0) {
            int b = br[i];
            unsigned pos = atomicAdd(&lcur[b], 1u);
            pair[gb[b] + pos] = make_float2(evr[i], __uint_as_float(auxr[i]));
        }
    }
}

// ================= K3b: within-bucket sort to per-node order + per-node offsets ===============
// Block b: stage bucket items in LDS, 128-entry histogram + scan, scatter to pair2
// (confined to this bucket's contiguous window -> XCD-local L2, write-amp ~1).
__global__ __launch_bounds__(256) void k3b_sort(const unsigned* __restrict__ offs_b,
                                                const float2* __restrict__ pair,
                                                float2* __restrict__ pair2,
                                                unsigned* __restrict__ offs_g) {
    __shared__ float2 items[BCAP];          // 24KB
    __shared__ unsigned hist[128], loffs[128], lcur[128], sd[128];
    const int t = threadIdx.x;
    const int b = blockIdx.x;
    const int lo = offs_b[b], hi = offs_b[b + 1], cnt = hi - lo;
    if (t < 128) { hist[t] = 0; lcur[t] = 0; }
    __syncthreads();
    for (int i = t; i < cnt; i += 256) {
        float2 it = pair[lo + i];
        items[i] = it;
        atomicAdd(&hist[__float_as_uint(it.y) >> 16], 1u);
    }
    __syncthreads();
    unsigned v = (t < 128) ? hist[t] : 0u;
    if (t < 128) sd[t] = v;
    __syncthreads();
#pragma unroll
    for (int off = 1; off < 128; off <<= 1) {
        unsigned tmp = (t >= off && t < 128) ? sd[t - off] : 0u;
        __syncthreads();
        if (t < 128) sd[t] += tmp;
        __syncthreads();
    }
    if (t < 128) {
        unsigned ex = sd[t] - v;
        loffs[t] = ex;
        offs_g[b * 128 + t] = lo + ex;
    }
    if (b == 0 && t == 128) offs_g[NB * 128] = N_EDGES;
    __syncthreads();
    for (int i = t; i < cnt; i += 256) {
        float2 it = items[i];
        unsigned dl = __float_as_uint(it.y) >> 16;
        unsigned pos = atomicAdd(&lcur[dl], 1u);
        pair2[lo + loffs[dl] + pos] = it;
    }
}

// ================= K4: wave-per-node segment aggregate (sorted pairs, 4x ILP) =================
__global__ __launch_bounds__(256) void k4_agg(const unsigned* __restrict__ offs_g,
                                              const float2* __restrict__ pair2,
                                              const __hip_bfloat16* __restrict__ zb,
                                              float* __restrict__ out) {
    const int lane = threadIdx.x & 63;
    const int wid = (blockIdx.x * blockDim.x + threadIdx.x) >> 6;
    const int nw = (gridDim.x * blockDim.x) >> 6;
    for (int n = wid; n < N_NODES; n += nw) {
        const int lo = offs_g[n], hi = offs_g[n + 1];
        float acc = 0.f, den = 0.f;
        int i = lo;
        for (; i + 3 < hi; i += 4) {
            float2 p0 = pair2[i];
            float2 p1 = pair2[i + 1];
            float2 p2 = pair2[i + 2];
            float2 p3 = pair2[i + 3];
            int s0 = __float_as_uint(p0.y) & 0xFFFF;
            int s1i = __float_as_uint(p1.y) & 0xFFFF;
            int s2i = __float_as_uint(p2.y) & 0xFFFF;
            int s3 = __float_as_uint(p3.y) & 0xFFFF;
            float z0 = __bfloat162float(zb[(size_t)s0 * OUT_DIM + lane]);
            float z1 = __bfloat162float(zb[(size_t)s1i * OUT_DIM + lane]);
            float z2 = __bfloat162float(zb[(size_t)s2i * OUT_DIM + lane]);
            float z3 = __bfloat162float(zb[(size_t)s3 * OUT_DIM + lane]);
            float e0 = __expf(p0.x), e1 = __expf(p1.x);
            float e2 = __expf(p2.x), e3 = __expf(p3.x);
            acc += e0 * z0 + e1 * z1 + e2 * z2 + e3 * z3;
            den += (e0 + e1) + (e2 + e3);
        }
        for (; i < hi; ++i) {
            float2 p0 = pair2[i];
            int s0 = __float_as_uint(p0.y) & 0xFFFF;
            float e0 = __expf(p0.x);
            acc += e0 * __bfloat162float(zb[(size_t)s0 * OUT_DIM + lane]);
            den += e0;
        }
        out[(size_t)n * OUT_DIM + lane] = (hi > lo) ? acc / den : 0.f;
    }
}

extern "C" void kernel_launch(void* const* d_in, const int* in_sizes, int n_in,
                              void* d_out, int out_size, void* d_ws, size_t ws_size,
                              hipStream_t stream) {
    const float* h     = (const float*)d_in[0];
    const float* p     = (const float*)d_in[1];
    const int*   src   = (const int*)d_in[2];
    const int*   dst   = (const int*)d_in[3];
    const float* Wfc   = (const float*)d_in[4];
    const float* Wattn = (const float*)d_in[5];
    float* out = (float*)d_out;

    // workspace layout (float words)
    float* ws = (float*)d_ws;
    __hip_bfloat16* zb = (__hip_bfloat16*)ws;        // 3,200,000 bf16 = 1,600,000 floats
    float*    s1     = ws + 1600000;                 // 50,000
    float*    s2     = ws + 1650000;                 // 50,000
    unsigned* gcount = (unsigned*)(ws + 1700000);    // 512
    unsigned* offs_b = (unsigned*)(ws + 1700512);    // 512 (NB+1 used)
    unsigned* ccur   = (unsigned*)(ws + 1701024);    // 6272 (391*16)
    unsigned* offs_g = (unsigned*)(ws + 1707296);    // 50,064 (NB*128+1 used)
    float2*   pair   = (float2*)(ws + 1757360);      // 800,000 float2
    float2*   pair2  = (float2*)(ws + 3357360);      // 800,000 float2
    // total: 4,957,360 floats = 19.8 MB

    hipMemsetAsync(gcount, 0, 512 * sizeof(unsigned), stream);

    k1_fc<<<(N_NODES + 63) / 64, 256, 0, stream>>>(h, Wfc, Wattn, zb, s1, s2);
    k2_count<<<K3_BLOCKS, 256, 0, stream>>>(dst, gcount);
    scan_buckets<<<1, 512, 0, stream>>>(gcount, offs_b, ccur);
    k3_fused<<<K3_BLOCKS, 256, 0, stream>>>(p, src, dst, Wattn, s1, s2, ccur, pair);
    k3b_sort<<<NB, 256, 0, stream>>>(offs_b, pair, pair2, offs_g);
    k4_agg<<<3125, 256, 0, stream>>>(offs_g, pair2, zb, out);
}